// Round 5
// baseline (2453.294 us; speedup 1.0000x reference)
//
#include <hip/hip_runtime.h>
#include <hip/hip_bf16.h>

#define T_STEPS 512
#define BATCH   1024
#define HD1     80
#define HD2     100

#define W1_DW   40                 // packed dwords per lstm1 row
#define HK2     46                 // padded per-half packed dwords, lstm2 (2*46=92 >= 90)
#define NR1     320
#define NR2     400

typedef _Float16 half2_t __attribute__((ext_vector_type(2)));

union HU { unsigned int u; half2_t h; };
static __device__ __forceinline__ half2_t bch(unsigned int u) { HU x; x.u = u; return x.h; }
static __device__ __forceinline__ unsigned int bcu(half2_t h) { HU x; x.h = h; return x.u; }

static __device__ __forceinline__ float dot2(half2_t a, half2_t b, float c) {
    return __builtin_amdgcn_fdot2(a, b, c, false);
}

static __device__ __forceinline__ unsigned int packh(float a, float b) {
    half2_t p; p.x = (_Float16)a; p.y = (_Float16)b; return bcu(p);
}

// ---------------------------------------------------------------------------
// Prep: pack weights to f16 dwords, transposed [dword][row].
// w1t[d*320+j]   : lstm1 row j, h pair (2d,2d+1),              d<40
// w2t[g*400+row] : lstm2 row, global k2 g: g<40 -> W_ih2 pair; 40<=g<90 ->
//                  W_hh2 pair (g-40); g>=90 -> zero pad.       g<92
// ---------------------------------------------------------------------------
__global__ __launch_bounds__(256)
void prep_kernel(const float* __restrict__ W_hh1,
                 const float* __restrict__ W_ih2,
                 const float* __restrict__ W_hh2,
                 unsigned int* __restrict__ w1t,
                 unsigned int* __restrict__ w2t)
{
    int i = blockIdx.x * 256 + threadIdx.x;
    if (i < W1_DW * NR1) {
        int d = i / NR1, j = i % NR1;
        w1t[i] = packh(W_hh1[j * HD1 + 2 * d], W_hh1[j * HD1 + 2 * d + 1]);
    } else if (i < W1_DW * NR1 + 2 * HK2 * NR2) {
        int k = i - W1_DW * NR1;
        int g = k / NR2, row = k % NR2;
        unsigned int p = 0u;
        if (g < 40)
            p = packh(W_ih2[row * HD1 + 2 * g], W_ih2[row * HD1 + 2 * g + 1]);
        else if (g < 90) {
            int gg = g - 40;
            p = packh(W_hh2[row * HD2 + 2 * gg], W_hh2[row * HD2 + 2 * gg + 1]);
        }
        w2t[k] = p;
    }
}

// ---------------------------------------------------------------------------
// Phase 1: LSTM layer 1, 2 batches/block (512 blocks x 320 threads).
// Thread j owns gate-row j; 40 weight dwords in VGPRs. State in LDS as
// dword[2*k2+b] (k2 pair index, b batch); read as uint4 broadcast.
// 4 independent dot2 chains. 2 barriers/step.
// ---------------------------------------------------------------------------
__global__ __launch_bounds__(NR1, 4)
void lstm1_kernel(const float* __restrict__ x,
                  const float* __restrict__ W_ih1,
                  const unsigned int* __restrict__ w1t,
                  const float* __restrict__ b_ih1,
                  const float* __restrict__ b_hh1,
                  _Float16* __restrict__ h1relu)
{
    const int j  = threadIdx.x;
    const int b0 = blockIdx.x * 2;
    const int q  = j / HD1;

    unsigned int w[W1_DW];
#pragma unroll
    for (int d = 0; d < W1_DW; d++) w[d] = w1t[d * NR1 + j];
    const float wih  = W_ih1[j];
    const float bias = b_ih1[j] + b_hh1[j];

    __shared__ unsigned int hpS[2 * HD1];   // dword 2*k2+b, k2<40
    __shared__ float2 gates[NR1];
    __shared__ float  xs[2][T_STEPS];

    if (j < 2 * HD1 / 2) { hpS[2 * j] = 0u; hpS[2 * j + 1] = 0u; }
    for (int idx = j; idx < 2 * T_STEPS; idx += NR1) {
        int b = idx >> 9, tt = idx & (T_STEPS - 1);
        xs[b][tt] = x[(size_t)(b0 + b) * T_STEPS + tt];
    }
    float c0 = 0.f, c1 = 0.f;
    __syncthreads();

    const uint4* hp4 = (const uint4*)hpS;
    for (int t = 0; t < T_STEPS; t++) {
        float a0 = fmaf(wih, xs[0][t], bias);
        float a1 = fmaf(wih, xs[1][t], bias);
        float a2 = 0.f, a3 = 0.f;
#pragma unroll
        for (int r = 0; r < W1_DW / 2; r++) {
            uint4 U = hp4[r];
            a0 = dot2(bch(w[2 * r]),     bch(U.x), a0);
            a1 = dot2(bch(w[2 * r]),     bch(U.y), a1);
            a2 = dot2(bch(w[2 * r + 1]), bch(U.z), a2);
            a3 = dot2(bch(w[2 * r + 1]), bch(U.w), a3);
        }
        float z0 = a0 + a2, z1 = a1 + a3;
        z0 = (q == 2) ? 2.f * z0 : z0;
        z1 = (q == 2) ? 2.f * z1 : z1;
        float e0 = 1.f / (1.f + __expf(-z0));
        float e1 = 1.f / (1.f + __expf(-z1));
        gates[j] = make_float2((q == 2) ? 2.f * e0 - 1.f : e0,
                               (q == 2) ? 2.f * e1 - 1.f : e1);
        __syncthreads();                    // gates ready

        if (j < HD1) {
            float2 gi = gates[j];
            float2 gf = gates[HD1 + j];
            float2 gg = gates[2 * HD1 + j];
            float2 go = gates[3 * HD1 + j];
            c0 = fmaf(gf.x, c0, gi.x * gg.x);
            c1 = fmaf(gf.y, c1, gi.y * gg.y);
            float t0 = 2.f / (1.f + __expf(-2.f * c0)) - 1.f;
            float t1 = 2.f / (1.f + __expf(-2.f * c1)) - 1.f;
            float h0 = go.x * t0;
            float h1 = go.y * t1;
            float h0n = __shfl_down(h0, 1, 64);
            float h1n = __shfl_down(h1, 1, 64);
            if ((j & 1) == 0) {
                // k2 = j/2 -> dwords j (b0 pair), j+1 (b1 pair)
                *(uint2*)&hpS[j] = make_uint2(packh(h0, h0n), packh(h1, h1n));
                *(unsigned int*)(h1relu + ((size_t)t * BATCH + b0)     * HD1 + j) =
                    packh(fmaxf(h0, 0.f), fmaxf(h0n, 0.f));
                *(unsigned int*)(h1relu + ((size_t)t * BATCH + b0 + 1) * HD1 + j) =
                    packh(fmaxf(h1, 0.f), fmaxf(h1n, 0.f));
            }
        }
        __syncthreads();                    // state(t+1) ready
    }
}

// ---------------------------------------------------------------------------
// Phase 2: LSTM layer 2, 2 batches/block (512 blocks x 896 threads).
// Split-K pairs: threads (2r, 2r+1) own row r halves (46 padded dwords each
// -> fits the compiler's 64-VGPR budget; no spill possible). Partials combine
// via shfl_xor(1). Threads 800..879 stage h1 with 1-step register prefetch.
// State LDS: dword[2*k2+b], k2: 0..39 h1, 40..89 h2, 90..91 pad.
// 2 barriers/step.
// ---------------------------------------------------------------------------
__global__ __launch_bounds__(896, 7)
void lstm2_kernel(const _Float16* __restrict__ h1relu,
                  const unsigned int* __restrict__ w2t,
                  const float* __restrict__ b_ih2,
                  const float* __restrict__ b_hh2,
                  float* __restrict__ h2last)
{
    const int j    = threadIdx.x;
    const int b0   = blockIdx.x * 2;
    const bool worker = (j < 2 * NR2);
    const int row  = worker ? (j >> 1) : 0;
    const int half = j & 1;

    unsigned int w[HK2];
#pragma unroll
    for (int d = 0; d < HK2; d++) w[d] = w2t[(half * HK2 + d) * NR2 + row];
    const float bias  = b_ih2[row] + b_hh2[row];
    const float bias0 = (half == 0) ? bias : 0.f;
    const int q = row / HD2;

    __shared__ unsigned int hpS[4 * HK2];   // 184 dwords
    __shared__ float2 gates[NR2];

    const int  sj = j - 2 * NR2;
    const bool stager = (sj >= 0) && (sj < 80);
    const int  pb = stager ? (sj / 40) : 0;
    const int  pk = stager ? (sj % 40) : 0;  // k2 index 0..39
    unsigned int pf = 0;
    if (stager) {
        pf = *(const unsigned int*)(h1relu + ((size_t)b0 + pb) * HD1 + 2 * pk);
        hpS[2 * pk + pb] = pf;              // stage h1(0)
    }
    if (j < 104) hpS[80 + j] = 0u;          // zero h2 + pads (dwords 80..183)
    float c0 = 0.f, c1 = 0.f;
    __syncthreads();
    if (stager)
        pf = *(const unsigned int*)(h1relu + ((size_t)1 * BATCH + b0 + pb) * HD1 + 2 * pk);

    const uint4* hp4 = (const uint4*)hpS;
    for (int t = 0; t < T_STEPS; t++) {
        float a0 = bias0, a1 = 0.f, a2 = 0.f, a3 = 0.f;
#pragma unroll
        for (int r = 0; r < HK2 / 2; r++) {           // 23 uint4 broadcast reads
            uint4 U = hp4[half * (HK2 / 2) + r];
            a0 = dot2(bch(w[2 * r]),     bch(U.x), a0);
            a1 = dot2(bch(w[2 * r]),     bch(U.y), a1);
            a2 = dot2(bch(w[2 * r + 1]), bch(U.z), a2);
            a3 = dot2(bch(w[2 * r + 1]), bch(U.w), a3);
        }
        float s0 = a0 + a2, s1 = a1 + a3;
        s0 += __shfl_xor(s0, 1, 64);                  // combine K-halves
        s1 += __shfl_xor(s1, 1, 64);
        float z0 = (q == 2) ? 2.f * s0 : s0;
        float z1 = (q == 2) ? 2.f * s1 : s1;
        float e0 = 1.f / (1.f + __expf(-z0));
        float e1 = 1.f / (1.f + __expf(-z1));
        if (worker && half == 0)
            gates[row] = make_float2((q == 2) ? 2.f * e0 - 1.f : e0,
                                     (q == 2) ? 2.f * e1 - 1.f : e1);
        __syncthreads();                              // barrier 1: gates ready

        if (j < HD2) {
            float2 gi = gates[j];
            float2 gf = gates[HD2 + j];
            float2 gg = gates[2 * HD2 + j];
            float2 go = gates[3 * HD2 + j];
            c0 = fmaf(gf.x, c0, gi.x * gg.x);
            c1 = fmaf(gf.y, c1, gi.y * gg.y);
            float t0 = 2.f / (1.f + __expf(-2.f * c0)) - 1.f;
            float t1 = 2.f / (1.f + __expf(-2.f * c1)) - 1.f;
            float h0 = go.x * t0;
            float h1 = go.y * t1;
            float h0n = __shfl_down(h0, 1, 64);
            float h1n = __shfl_down(h1, 1, 64);
            if ((j & 1) == 0) {
                // k2 = 40 + j/2 -> dwords 80+j, 81+j
                *(uint2*)&hpS[80 + j] = make_uint2(packh(h0, h0n), packh(h1, h1n));
            }
            if (t == T_STEPS - 1) {
                h2last[(size_t)(b0 + 0) * HD2 + j] = fmaxf(h0, 0.f);
                h2last[(size_t)(b0 + 1) * HD2 + j] = fmaxf(h1, 0.f);
            }
        }
        if (stager && (t + 1 < T_STEPS))
            hpS[2 * pk + pb] = pf;                    // stage h1(t+1)
        if (stager && (t + 2 < T_STEPS))
            pf = *(const unsigned int*)(h1relu +
                     ((size_t)(t + 2) * BATCH + b0 + pb) * HD1 + 2 * pk);
        __syncthreads();                              // barrier 2: state(t+1)
    }
}

// ---------------------------------------------------------------------------
// Head: out[b] = W_l2 @ relu(W_l1 @ h2last[b] + b_l1) + b_l2
// ---------------------------------------------------------------------------
__global__ __launch_bounds__(64)
void head_kernel(const float* __restrict__ h2last,
                 const float* __restrict__ W_l1,
                 const float* __restrict__ b_l1,
                 const float* __restrict__ W_l2,
                 const float* __restrict__ b_l2,
                 float* __restrict__ out)
{
    int b = blockIdx.x * 64 + threadIdx.x;
    if (b >= BATCH) return;
    const float* h = h2last + (size_t)b * HD2;
    float o = b_l2[0];
#pragma unroll
    for (int u = 0; u < 10; u++) {
        float s = b_l1[u];
#pragma unroll
        for (int k = 0; k < HD2; k++) s = fmaf(W_l1[u * HD2 + k], h[k], s);
        o = fmaf(W_l2[u], fmaxf(s, 0.f), o);
    }
    out[b] = o;
}

extern "C" void kernel_launch(void* const* d_in, const int* in_sizes, int n_in,
                              void* d_out, int out_size, void* d_ws, size_t ws_size,
                              hipStream_t stream)
{
    const float* x     = (const float*)d_in[0];
    const float* W_ih1 = (const float*)d_in[1];
    const float* W_hh1 = (const float*)d_in[2];
    const float* b_ih1 = (const float*)d_in[3];
    const float* b_hh1 = (const float*)d_in[4];
    const float* W_ih2 = (const float*)d_in[5];
    const float* W_hh2 = (const float*)d_in[6];
    const float* b_ih2 = (const float*)d_in[7];
    const float* b_hh2 = (const float*)d_in[8];
    const float* W_l1  = (const float*)d_in[9];
    const float* b_l1  = (const float*)d_in[10];
    const float* W_l2  = (const float*)d_in[11];
    const float* b_l2  = (const float*)d_in[12];
    float* out = (float*)d_out;

    // ws layout: h1relu f16 [t][b][k] (84 MB) | h2last f32 | w1t | w2t
    char* p = (char*)d_ws;
    _Float16* h1relu = (_Float16*)p;           p += (size_t)T_STEPS * BATCH * HD1 * 2;
    float* h2last    = (float*)p;              p += (size_t)BATCH * HD2 * 4;
    unsigned int* w1t = (unsigned int*)p;      p += (size_t)W1_DW * NR1 * 4;
    unsigned int* w2t = (unsigned int*)p;

    int prep_n = W1_DW * NR1 + 2 * HK2 * NR2;
    hipLaunchKernelGGL(prep_kernel, dim3((prep_n + 255) / 256), dim3(256), 0, stream,
                       W_hh1, W_ih2, W_hh2, w1t, w2t);
    hipLaunchKernelGGL(lstm1_kernel, dim3(BATCH / 2), dim3(NR1), 0, stream,
                       x, W_ih1, w1t, b_ih1, b_hh1, h1relu);
    hipLaunchKernelGGL(lstm2_kernel, dim3(BATCH / 2), dim3(896), 0, stream,
                       h1relu, w2t, b_ih2, b_hh2, h2last);
    hipLaunchKernelGGL(head_kernel, dim3(BATCH / 64), dim3(64), 0, stream,
                       h2last, W_l1, b_l1, W_l2, b_l2, out);
}

// Round 6
// 2227.234 us; speedup vs baseline: 1.1015x; 1.1015x over previous
//
#include <hip/hip_runtime.h>
#include <hip/hip_bf16.h>

#define T_STEPS 512
#define BATCH   1024
#define HD1     80
#define HD2     100
#define NB      2       // batches per block (lstm2)

#define W1_DW   (HD1 / 2)              // 40 packed dwords per lstm1 row
#define W2_DW   ((HD1 + HD2) / 2)      // 90 packed dwords per lstm2 row
#define NR1     (4 * HD1)              // 320 rows
#define NR2     (4 * HD2)              // 400 rows

typedef _Float16 half2_t __attribute__((ext_vector_type(2)));

union HU { unsigned int u; half2_t h; };
static __device__ __forceinline__ half2_t bch(unsigned int u) { HU x; x.u = u; return x.h; }
static __device__ __forceinline__ unsigned int bcu(half2_t h) { HU x; x.h = h; return x.u; }

static __device__ __forceinline__ float dot2(half2_t a, half2_t b, float c) {
    return __builtin_amdgcn_fdot2(a, b, c, false);
}

static __device__ __forceinline__ unsigned int packh(float a, float b) {
    half2_t p; p.x = (_Float16)a; p.y = (_Float16)b; return bcu(p);
}

// ---------------------------------------------------------------------------
// Prep: pack weights to f16 dwords, transposed [dword][row] for coalescing.
// ---------------------------------------------------------------------------
__global__ __launch_bounds__(256)
void prep_kernel(const float* __restrict__ W_hh1,
                 const float* __restrict__ W_ih2,
                 const float* __restrict__ W_hh2,
                 unsigned int* __restrict__ w1t,
                 unsigned int* __restrict__ w2t)
{
    int i = blockIdx.x * 256 + threadIdx.x;
    if (i < W1_DW * NR1) {
        int d = i / NR1, j = i % NR1;
        w1t[i] = packh(W_hh1[j * HD1 + 2 * d], W_hh1[j * HD1 + 2 * d + 1]);
    } else if (i < W1_DW * NR1 + W2_DW * NR2) {
        int k = i - W1_DW * NR1;
        int d = k / NR2, j = k % NR2;
        unsigned int p;
        if (d < W1_DW)
            p = packh(W_ih2[j * HD1 + 2 * d], W_ih2[j * HD1 + 2 * d + 1]);
        else {
            int dd = d - W1_DW;
            p = packh(W_hh2[j * HD2 + 2 * dd], W_hh2[j * HD2 + 2 * dd + 1]);
        }
        w2t[k] = p;
    }
}

// ---------------------------------------------------------------------------
// Phase 1: LSTM layer 1, ONE batch per block (1024 blocks x 320 threads).
// (Identical to round 4 — known-good perf and numerics.)
// ---------------------------------------------------------------------------
__global__ __launch_bounds__(NR1, 4)
void lstm1_kernel(const float* __restrict__ x,
                  const float* __restrict__ W_ih1,
                  const unsigned int* __restrict__ w1t,
                  const float* __restrict__ b_ih1,
                  const float* __restrict__ b_hh1,
                  _Float16* __restrict__ h1relu)
{
    const int j = threadIdx.x;
    const int b = blockIdx.x;
    const int q = j / HD1;
    const int m = j % HD1;

    unsigned int w[W1_DW];
#pragma unroll
    for (int d = 0; d < W1_DW; d++) w[d] = w1t[d * NR1 + j];
    const float wih  = W_ih1[j];
    const float bias = b_ih1[j] + b_hh1[j];

    __shared__ uint4 hp[HD1 / 8];     // 10 entries, 8 f16 values each
    __shared__ float gates[NR1];
    __shared__ float xs[T_STEPS];

    if (j < HD1 / 8) hp[j] = make_uint4(0u, 0u, 0u, 0u);
    for (int idx = j; idx < T_STEPS; idx += NR1)
        xs[idx] = x[(size_t)b * T_STEPS + idx];
    float c = 0.f;
    __syncthreads();

    for (int t = 0; t < T_STEPS; t++) {
        float accP = fmaf(wih, xs[t], bias);
        float accQ = 0.f;
#pragma unroll
        for (int k4 = 0; k4 < HD1 / 8; k4++) {
            uint4 U = hp[k4];
            accP = dot2(bch(w[4 * k4 + 0]), bch(U.x), accP);
            accQ = dot2(bch(w[4 * k4 + 1]), bch(U.y), accQ);
            accP = dot2(bch(w[4 * k4 + 2]), bch(U.z), accP);
            accQ = dot2(bch(w[4 * k4 + 3]), bch(U.w), accQ);
        }
        float z = accP + accQ;
        z = (q == 2) ? 2.f * z : z;
        float s = 1.f / (1.f + __expf(-z));
        gates[j] = (q == 2) ? (2.f * s - 1.f) : s;
        __syncthreads();                      // gates ready

        if (j < HD1) {
            float gi = gates[m];
            float gf = gates[HD1 + m];
            float gg = gates[2 * HD1 + m];
            float go = gates[3 * HD1 + m];
            c = fmaf(gf, c, gi * gg);
            float th = 2.f / (1.f + __expf(-2.f * c)) - 1.f;
            float h = go * th;
            float hn = __shfl_down(h, 1, 64);
            if ((m & 1) == 0) {
                ((unsigned int*)hp)[m >> 1] = packh(h, hn);
                *(unsigned int*)(h1relu + ((size_t)t * BATCH + b) * HD1 + m) =
                    packh(fmaxf(h, 0.f), fmaxf(hn, 0.f));
            }
        }
        __syncthreads();                      // hp(t+1) ready
    }
}

// ---------------------------------------------------------------------------
// Phase 2: LSTM layer 2. 512 blocks x 512 threads, 2 batches/block.
// Identical to round 4 EXCEPT __launch_bounds__(512,2): allocator grants
// ~112 VGPRs (observed round 1) so the 90 weight dwords stay register-
// resident instead of spilling (round 4 at (512,4) gave 64 regs + 131 MB
// scratch writes).
// ---------------------------------------------------------------------------
__global__ __launch_bounds__(512, 2)
void lstm2_kernel(const _Float16* __restrict__ h1relu,
                  const unsigned int* __restrict__ w2t,
                  const float* __restrict__ b_ih2,
                  const float* __restrict__ b_hh2,
                  float* __restrict__ h2last)
{
    const int j  = threadIdx.x;
    const int b0 = blockIdx.x * NB;
    const int jr = (j < NR2) ? j : (NR2 - 1);   // clamp: loads unconditional
    const bool rowActive = (j < NR2);
    const int q = jr / HD2;
    const int m = jr % HD2;

    unsigned int w[W2_DW];
#pragma unroll
    for (int d = 0; d < W2_DW; d++) w[d] = w2t[d * NR2 + jr];
    const float bias = b_ih2[jr] + b_hh2[jr];

    __shared__ uint4  h1p[HD1 / 4];    // 20 entries: {b0 pair, b1 pair, b0 pair, b1 pair}
    __shared__ uint4  h2p[HD2 / 4];    // 25 entries, same layout
    __shared__ float2 gates[NR2];

    if (j < HD2 / 4) h2p[j] = make_uint4(0u, 0u, 0u, 0u);
    float c0 = 0.f, c1 = 0.f;

    // stagers: threads 400..479
    const int  sj = j - NR2;
    const bool stager = (sj >= 0) && (sj < NB * W1_DW);
    const int  pb  = (sj >= 0 ? sj : 0) / W1_DW;
    const int  pk2 = (sj >= 0 ? sj : 0) % W1_DW;
    const int  sidx = 4 * (pk2 >> 1) + 2 * (pk2 & 1) + pb;
    unsigned int pf = 0;
    if (stager)
        pf = *(const unsigned int*)(h1relu + ((size_t)b0 + pb) * HD1 + 2 * pk2);

    for (int t = 0; t < T_STEPS; t++) {
        if (stager)
            ((unsigned int*)h1p)[sidx] = pf;   // stage h1(t)
        __syncthreads();                       // h1p(t) + h2p(t) ready

        if (stager && t + 1 < T_STEPS)
            pf = *(const unsigned int*)(h1relu +
                     ((size_t)(t + 1) * BATCH + b0 + pb) * HD1 + 2 * pk2);

        // dots on ALL threads (uniform control flow; garbage for j>=400)
        float a0P = bias, a0Q = 0.f, a1P = bias, a1Q = 0.f;
#pragma unroll
        for (int k4 = 0; k4 < HD1 / 4; k4++) {
            uint4 U = h1p[k4];
            a0P = dot2(bch(w[2 * k4]),     bch(U.x), a0P);
            a1P = dot2(bch(w[2 * k4]),     bch(U.y), a1P);
            a0Q = dot2(bch(w[2 * k4 + 1]), bch(U.z), a0Q);
            a1Q = dot2(bch(w[2 * k4 + 1]), bch(U.w), a1Q);
        }
#pragma unroll
        for (int k4 = 0; k4 < HD2 / 4; k4++) {
            uint4 U = h2p[k4];
            a0P = dot2(bch(w[W1_DW + 2 * k4]),     bch(U.x), a0P);
            a1P = dot2(bch(w[W1_DW + 2 * k4]),     bch(U.y), a1P);
            a0Q = dot2(bch(w[W1_DW + 2 * k4 + 1]), bch(U.z), a0Q);
            a1Q = dot2(bch(w[W1_DW + 2 * k4 + 1]), bch(U.w), a1Q);
        }
        float z0 = a0P + a0Q;
        float z1 = a1P + a1Q;
        z0 = (q == 2) ? 2.f * z0 : z0;
        z1 = (q == 2) ? 2.f * z1 : z1;
        float s0 = 1.f / (1.f + __expf(-z0));
        float s1 = 1.f / (1.f + __expf(-z1));
        if (rowActive)
            gates[j] = make_float2((q == 2) ? (2.f * s0 - 1.f) : s0,
                                   (q == 2) ? (2.f * s1 - 1.f) : s1);
        __syncthreads();                       // gates ready

        if (j < HD2) {
            float2 gi = gates[m];
            float2 gf = gates[HD2 + m];
            float2 gg = gates[2 * HD2 + m];
            float2 go = gates[3 * HD2 + m];
            c0 = fmaf(gf.x, c0, gi.x * gg.x);
            c1 = fmaf(gf.y, c1, gi.y * gg.y);
            float t0 = 2.f / (1.f + __expf(-2.f * c0)) - 1.f;
            float t1 = 2.f / (1.f + __expf(-2.f * c1)) - 1.f;
            float h0 = go.x * t0;
            float h1 = go.y * t1;
            float h0n = __shfl_down(h0, 1, 64);
            float h1n = __shfl_down(h1, 1, 64);
            if ((m & 1) == 0) {
                int p = m >> 1;
                int idx0 = 4 * (p >> 1) + 2 * (p & 1);   // even → uint2-aligned
                ((uint2*)h2p)[idx0 >> 1] =
                    make_uint2(packh(h0, h0n), packh(h1, h1n));
            }
            if (t == T_STEPS - 1) {
                h2last[(size_t)(b0 + 0) * HD2 + m] = fmaxf(h0, 0.f);
                h2last[(size_t)(b0 + 1) * HD2 + m] = fmaxf(h1, 0.f);
            }
        }
        // next loop-top stage + barrier covers h2p visibility
    }
}

// ---------------------------------------------------------------------------
// Head: out[b] = W_l2 @ relu(W_l1 @ h2last[b] + b_l1) + b_l2
// ---------------------------------------------------------------------------
__global__ __launch_bounds__(64)
void head_kernel(const float* __restrict__ h2last,
                 const float* __restrict__ W_l1,
                 const float* __restrict__ b_l1,
                 const float* __restrict__ W_l2,
                 const float* __restrict__ b_l2,
                 float* __restrict__ out)
{
    int b = blockIdx.x * 64 + threadIdx.x;
    if (b >= BATCH) return;
    const float* h = h2last + (size_t)b * HD2;
    float o = b_l2[0];
#pragma unroll
    for (int u = 0; u < 10; u++) {
        float s = b_l1[u];
#pragma unroll
        for (int k = 0; k < HD2; k++) s = fmaf(W_l1[u * HD2 + k], h[k], s);
        o = fmaf(W_l2[u], fmaxf(s, 0.f), o);
    }
    out[b] = o;
}

extern "C" void kernel_launch(void* const* d_in, const int* in_sizes, int n_in,
                              void* d_out, int out_size, void* d_ws, size_t ws_size,
                              hipStream_t stream)
{
    const float* x     = (const float*)d_in[0];
    const float* W_ih1 = (const float*)d_in[1];
    const float* W_hh1 = (const float*)d_in[2];
    const float* b_ih1 = (const float*)d_in[3];
    const float* b_hh1 = (const float*)d_in[4];
    const float* W_ih2 = (const float*)d_in[5];
    const float* W_hh2 = (const float*)d_in[6];
    const float* b_ih2 = (const float*)d_in[7];
    const float* b_hh2 = (const float*)d_in[8];
    const float* W_l1  = (const float*)d_in[9];
    const float* b_l1  = (const float*)d_in[10];
    const float* W_l2  = (const float*)d_in[11];
    const float* b_l2  = (const float*)d_in[12];
    float* out = (float*)d_out;

    // ws layout: h1relu f16 [t][b][k] (84 MB) | h2last f32 | w1t | w2t
    char* p = (char*)d_ws;
    _Float16* h1relu = (_Float16*)p;           p += (size_t)T_STEPS * BATCH * HD1 * 2;
    float* h2last    = (float*)p;              p += (size_t)BATCH * HD2 * 4;
    unsigned int* w1t = (unsigned int*)p;      p += (size_t)W1_DW * NR1 * 4;
    unsigned int* w2t = (unsigned int*)p;

    int prep_n = W1_DW * NR1 + W2_DW * NR2;
    hipLaunchKernelGGL(prep_kernel, dim3((prep_n + 255) / 256), dim3(256), 0, stream,
                       W_hh1, W_ih2, W_hh2, w1t, w2t);
    hipLaunchKernelGGL(lstm1_kernel, dim3(BATCH), dim3(NR1), 0, stream,
                       x, W_ih1, w1t, b_ih1, b_hh1, h1relu);
    hipLaunchKernelGGL(lstm2_kernel, dim3(BATCH / NB), dim3(512), 0, stream,
                       h1relu, w2t, b_ih2, b_hh2, h2last);
    hipLaunchKernelGGL(head_kernel, dim3(BATCH / 64), dim3(64), 0, stream,
                       h2last, W_l1, b_l1, W_l2, b_l2, out);
}

// Round 7
// 1899.165 us; speedup vs baseline: 1.2918x; 1.1727x over previous
//
#include <hip/hip_runtime.h>
#include <hip/hip_bf16.h>

#define T_STEPS 512
#define BATCH   1024
#define HD1     80
#define HD2     100

#define W1_DW   40                 // packed dwords per lstm1 row (K=80)
#define W2_DW   90                 // packed dwords per lstm2 row (40 ih + 50 hh)
#define NR1     320
#define NR2     400

typedef _Float16 half2_t __attribute__((ext_vector_type(2)));

union HU { unsigned int u; half2_t h; };
static __device__ __forceinline__ half2_t bch(unsigned int u) { HU x; x.u = u; return x.h; }
static __device__ __forceinline__ unsigned int bcu(half2_t h) { HU x; x.h = h; return x.u; }

static __device__ __forceinline__ float dot2(half2_t a, half2_t b, float c) {
    return __builtin_amdgcn_fdot2(a, b, c, false);
}

static __device__ __forceinline__ unsigned int packh(float a, float b) {
    half2_t p; p.x = (_Float16)a; p.y = (_Float16)b; return bcu(p);
}

// ---------------------------------------------------------------------------
// Prep: pack weights to f16 dwords, transposed [dword][row] (round-6 layout).
// w2t: d<40 = W_ih2 pair d; 40<=d<90 = W_hh2 pair (d-40).
// ---------------------------------------------------------------------------
__global__ __launch_bounds__(256)
void prep_kernel(const float* __restrict__ W_hh1,
                 const float* __restrict__ W_ih2,
                 const float* __restrict__ W_hh2,
                 unsigned int* __restrict__ w1t,
                 unsigned int* __restrict__ w2t)
{
    int i = blockIdx.x * 256 + threadIdx.x;
    if (i < W1_DW * NR1) {
        int d = i / NR1, j = i % NR1;
        w1t[i] = packh(W_hh1[j * HD1 + 2 * d], W_hh1[j * HD1 + 2 * d + 1]);
    } else if (i < W1_DW * NR1 + W2_DW * NR2) {
        int k = i - W1_DW * NR1;
        int d = k / NR2, j = k % NR2;
        unsigned int p;
        if (d < W1_DW)
            p = packh(W_ih2[j * HD1 + 2 * d], W_ih2[j * HD1 + 2 * d + 1]);
        else {
            int dd = d - W1_DW;
            p = packh(W_hh2[j * HD2 + 2 * dd], W_hh2[j * HD2 + 2 * dd + 1]);
        }
        w2t[k] = p;
    }
}

// ---------------------------------------------------------------------------
// Phase 1: LSTM layer 1 (round-6 proven version, unchanged).
// ---------------------------------------------------------------------------
__global__ __launch_bounds__(NR1, 4)
void lstm1_kernel(const float* __restrict__ x,
                  const float* __restrict__ W_ih1,
                  const unsigned int* __restrict__ w1t,
                  const float* __restrict__ b_ih1,
                  const float* __restrict__ b_hh1,
                  _Float16* __restrict__ h1relu)
{
    const int j = threadIdx.x;
    const int b = blockIdx.x;
    const int q = j / HD1;
    const int m = j % HD1;

    unsigned int w[W1_DW];
#pragma unroll
    for (int d = 0; d < W1_DW; d++) w[d] = w1t[d * NR1 + j];
    const float wih  = W_ih1[j];
    const float bias = b_ih1[j] + b_hh1[j];

    __shared__ uint4 hp[HD1 / 8];
    __shared__ float gates[NR1];
    __shared__ float xs[T_STEPS];

    if (j < HD1 / 8) hp[j] = make_uint4(0u, 0u, 0u, 0u);
    for (int idx = j; idx < T_STEPS; idx += NR1)
        xs[idx] = x[(size_t)b * T_STEPS + idx];
    float c = 0.f;
    __syncthreads();

    for (int t = 0; t < T_STEPS; t++) {
        float accP = fmaf(wih, xs[t], bias);
        float accQ = 0.f;
#pragma unroll
        for (int k4 = 0; k4 < HD1 / 8; k4++) {
            uint4 U = hp[k4];
            accP = dot2(bch(w[4 * k4 + 0]), bch(U.x), accP);
            accQ = dot2(bch(w[4 * k4 + 1]), bch(U.y), accQ);
            accP = dot2(bch(w[4 * k4 + 2]), bch(U.z), accP);
            accQ = dot2(bch(w[4 * k4 + 3]), bch(U.w), accQ);
        }
        float z = accP + accQ;
        z = (q == 2) ? 2.f * z : z;
        float s = 1.f / (1.f + __expf(-z));
        gates[j] = (q == 2) ? (2.f * s - 1.f) : s;
        __syncthreads();

        if (j < HD1) {
            float gi = gates[m];
            float gf = gates[HD1 + m];
            float gg = gates[2 * HD1 + m];
            float go = gates[3 * HD1 + m];
            c = fmaf(gf, c, gi * gg);
            float th = 2.f / (1.f + __expf(-2.f * c)) - 1.f;
            float h = go * th;
            float hn = __shfl_down(h, 1, 64);
            if ((m & 1) == 0) {
                ((unsigned int*)hp)[m >> 1] = packh(h, hn);
                *(unsigned int*)(h1relu + ((size_t)t * BATCH + b) * HD1 + m) =
                    packh(fmaxf(h, 0.f), fmaxf(hn, 0.f));
            }
        }
        __syncthreads();
    }
}

// ---------------------------------------------------------------------------
// xg2 GEMM (time-parallel input projection for layer 2):
// xg2c[tc][b][row] = f16( b_ih2[row]+b_hh2[row] + W_ih2[row,:] . relu_h1[t,b,:] )
// 1024 blocks x 512 threads; workers 0..399 hold W_ih2 row (40 dwords, regs);
// threads 400..479 stage two h1 rows (80 dwords) per iter with reg prefetch.
// ---------------------------------------------------------------------------
__global__ __launch_bounds__(512, 2)
void xg2_kernel(const unsigned int* __restrict__ h1dw,   // h1relu as dwords
                const unsigned int* __restrict__ w2t,
                const float* __restrict__ b_ih2,
                const float* __restrict__ b_hh2,
                _Float16* __restrict__ xg2c,
                int t0, int IT)
{
    const int tid = threadIdx.x;
    const int jr  = (tid < NR2) ? tid : (NR2 - 1);

    unsigned int w[W1_DW];
#pragma unroll
    for (int d = 0; d < W1_DW; d++) w[d] = w2t[d * NR2 + jr];
    const float bias = b_ih2[jr] + b_hh2[jr];

    __shared__ unsigned int hbuf[2 * W1_DW];   // tb0 dwords 0..39, tb1 40..79

    const int cfBase = blockIdx.x * 2 * IT;    // chunk-flat (t,b) index base
    const long long gBase = ((long long)t0 * BATCH + cfBase) * W1_DW;
    const int  s = tid - NR2;
    const bool stager = (s >= 0) && (s < 2 * W1_DW);
    unsigned int pf = 0;
    if (stager) pf = h1dw[gBase + s];

    for (int it = 0; it < IT; it++) {
        if (stager) hbuf[s] = pf;
        __syncthreads();
        if (stager && it + 1 < IT)
            pf = h1dw[gBase + (long long)(it + 1) * (2 * W1_DW) + s];

        const uint4* hb = (const uint4*)hbuf;
        float a0 = bias, a1 = 0.f;    // tb0, two chains
        float a2 = bias, a3 = 0.f;    // tb1
#pragma unroll
        for (int r = 0; r < W1_DW / 4; r++) {
            uint4 U = hb[r];
            a0 = dot2(bch(w[4 * r + 0]), bch(U.x), a0);
            a1 = dot2(bch(w[4 * r + 1]), bch(U.y), a1);
            a0 = dot2(bch(w[4 * r + 2]), bch(U.z), a0);
            a1 = dot2(bch(w[4 * r + 3]), bch(U.w), a1);
        }
#pragma unroll
        for (int r = 0; r < W1_DW / 4; r++) {
            uint4 U = hb[W1_DW / 4 + r];
            a2 = dot2(bch(w[4 * r + 0]), bch(U.x), a2);
            a3 = dot2(bch(w[4 * r + 1]), bch(U.y), a3);
            a2 = dot2(bch(w[4 * r + 2]), bch(U.z), a2);
            a3 = dot2(bch(w[4 * r + 3]), bch(U.w), a3);
        }
        if (tid < NR2) {
            long long cf = cfBase + 2 * it;
            xg2c[cf * NR2 + tid]       = (_Float16)(a0 + a1);
            xg2c[(cf + 1) * NR2 + tid] = (_Float16)(a2 + a3);
        }
        __syncthreads();
    }
}

// ---------------------------------------------------------------------------
// Phase 2 sequential: only the K=100 recurrence. 512 blocks x 448 threads,
// 2 batches/block. Workers own rows with W_hh2 = 50 dwords in regs
// (fits the 112-reg (448,2) budget -> no spill). xg2 streamed from global
// with 1-step register prefetch. c/h2 persisted across T-chunks.
// ---------------------------------------------------------------------------
__global__ __launch_bounds__(448, 2)
void lstm2_kernel(const _Float16* __restrict__ xg2c,
                  const unsigned int* __restrict__ w2t,
                  float* __restrict__ cstate,
                  uint4* __restrict__ hstate,
                  float* __restrict__ h2last,
                  int CH, int first, int last)
{
    const int j  = threadIdx.x;
    const int b0 = blockIdx.x * 2;
    const int jr = (j < NR2) ? j : (NR2 - 1);
    const int q  = jr / HD2;
    const int m  = jr % HD2;

    unsigned int w[50];
#pragma unroll
    for (int d = 0; d < 50; d++) w[d] = w2t[(W1_DW + d) * NR2 + jr];

    __shared__ uint4  h2p[HD2 / 4];    // 25: {p(2k)b0, p(2k)b1, p(2k+1)b0, p(2k+1)b1}
    __shared__ float2 gates[NR2];

    float c0 = 0.f, c1 = 0.f;
    if (first) {
        if (j < HD2 / 4) h2p[j] = make_uint4(0u, 0u, 0u, 0u);
    } else {
        if (j < HD2 / 4) h2p[j] = hstate[blockIdx.x * (HD2 / 4) + j];
        if (j < HD2) {
            c0 = cstate[blockIdx.x * 2 * HD2 + j];
            c1 = cstate[blockIdx.x * 2 * HD2 + HD2 + j];
        }
    }
    __syncthreads();

    const _Float16* xgB = xg2c + (long long)b0 * NR2;
    float pf0 = (float)xgB[jr];
    float pf1 = (float)xgB[NR2 + jr];

    for (int t = 0; t < CH; t++) {
        float a0 = pf0, a1 = pf1, a2 = 0.f, a3 = 0.f;
        if (t + 1 < CH) {      // issue next-step loads early (hidden under dots)
            pf0 = (float)xgB[(long long)(t + 1) * (BATCH * NR2) + jr];
            pf1 = (float)xgB[(long long)(t + 1) * (BATCH * NR2) + NR2 + jr];
        }
#pragma unroll
        for (int k4 = 0; k4 < HD2 / 4; k4++) {
            uint4 U = h2p[k4];
            a0 = dot2(bch(w[2 * k4]),     bch(U.x), a0);
            a1 = dot2(bch(w[2 * k4]),     bch(U.y), a1);
            a2 = dot2(bch(w[2 * k4 + 1]), bch(U.z), a2);
            a3 = dot2(bch(w[2 * k4 + 1]), bch(U.w), a3);
        }
        float z0 = a0 + a2;
        float z1 = a1 + a3;
        z0 = (q == 2) ? 2.f * z0 : z0;
        z1 = (q == 2) ? 2.f * z1 : z1;
        float s0 = 1.f / (1.f + __expf(-z0));
        float s1 = 1.f / (1.f + __expf(-z1));
        if (j < NR2)
            gates[j] = make_float2((q == 2) ? (2.f * s0 - 1.f) : s0,
                                   (q == 2) ? (2.f * s1 - 1.f) : s1);
        __syncthreads();                       // gates ready

        if (j < HD2) {
            float2 gi = gates[m];
            float2 gf = gates[HD2 + m];
            float2 gg = gates[2 * HD2 + m];
            float2 go = gates[3 * HD2 + m];
            c0 = fmaf(gf.x, c0, gi.x * gg.x);
            c1 = fmaf(gf.y, c1, gi.y * gg.y);
            float t0_ = 2.f / (1.f + __expf(-2.f * c0)) - 1.f;
            float t1_ = 2.f / (1.f + __expf(-2.f * c1)) - 1.f;
            float h0 = go.x * t0_;
            float h1 = go.y * t1_;
            float h0n = __shfl_down(h0, 1, 64);
            float h1n = __shfl_down(h1, 1, 64);
            if ((m & 1) == 0) {
                int p = m >> 1;
                int idx0 = 4 * (p >> 1) + 2 * (p & 1);
                ((uint2*)h2p)[idx0 >> 1] =
                    make_uint2(packh(h0, h0n), packh(h1, h1n));
            }
            if (last && t == CH - 1) {
                h2last[(size_t)(b0 + 0) * HD2 + m] = fmaxf(h0, 0.f);
                h2last[(size_t)(b0 + 1) * HD2 + m] = fmaxf(h1, 0.f);
            }
        }
        __syncthreads();                       // h2p(t+1) ready
    }

    // persist chunk state
    if (j < HD2 / 4) hstate[blockIdx.x * (HD2 / 4) + j] = h2p[j];
    if (j < HD2) {
        cstate[blockIdx.x * 2 * HD2 + j]       = c0;
        cstate[blockIdx.x * 2 * HD2 + HD2 + j] = c1;
    }
}

// ---------------------------------------------------------------------------
// Head: out[b] = W_l2 @ relu(W_l1 @ h2last[b] + b_l1) + b_l2
// ---------------------------------------------------------------------------
__global__ __launch_bounds__(64)
void head_kernel(const float* __restrict__ h2last,
                 const float* __restrict__ W_l1,
                 const float* __restrict__ b_l1,
                 const float* __restrict__ W_l2,
                 const float* __restrict__ b_l2,
                 float* __restrict__ out)
{
    int b = blockIdx.x * 64 + threadIdx.x;
    if (b >= BATCH) return;
    const float* h = h2last + (size_t)b * HD2;
    float o = b_l2[0];
#pragma unroll
    for (int u = 0; u < 10; u++) {
        float s = b_l1[u];
#pragma unroll
        for (int k = 0; k < HD2; k++) s = fmaf(W_l1[u * HD2 + k], h[k], s);
        o = fmaf(W_l2[u], fmaxf(s, 0.f), o);
    }
    out[b] = o;
}

extern "C" void kernel_launch(void* const* d_in, const int* in_sizes, int n_in,
                              void* d_out, int out_size, void* d_ws, size_t ws_size,
                              hipStream_t stream)
{
    const float* x     = (const float*)d_in[0];
    const float* W_ih1 = (const float*)d_in[1];
    const float* W_hh1 = (const float*)d_in[2];
    const float* b_ih1 = (const float*)d_in[3];
    const float* b_hh1 = (const float*)d_in[4];
    const float* W_ih2 = (const float*)d_in[5];
    const float* W_hh2 = (const float*)d_in[6];
    const float* b_ih2 = (const float*)d_in[7];
    const float* b_hh2 = (const float*)d_in[8];
    const float* W_l1  = (const float*)d_in[9];
    const float* b_l1  = (const float*)d_in[10];
    const float* W_l2  = (const float*)d_in[11];
    const float* b_l2  = (const float*)d_in[12];
    float* out = (float*)d_out;

    // ws layout (256B aligned blocks):
    //   h1relu f16 [t][b][80]   83,886,080
    //   h2last f32              409,600
    //   w1t                     51,200
    //   w2t                     144,000
    //   cstate f32 [512][200]   409,600
    //   hstate uint4 [512][25]  204,800
    //   xg2c f16 [CHUNK][1024][400]  CHUNK*819,200
    char* p = (char*)d_ws;
    auto take = [&](size_t n) { char* q = p; p += (n + 255) & ~(size_t)255; return q; };
    _Float16*     h1relu = (_Float16*)take((size_t)T_STEPS * BATCH * HD1 * 2);
    float*        h2last = (float*)take((size_t)BATCH * HD2 * 4);
    unsigned int* w1t    = (unsigned int*)take((size_t)W1_DW * NR1 * 4);
    unsigned int* w2t    = (unsigned int*)take((size_t)W2_DW * NR2 * 4);
    float*        cstate = (float*)take((size_t)512 * 2 * HD2 * 4);
    uint4*        hstate = (uint4*)take((size_t)512 * (HD2 / 4) * 16);
    size_t fixedBytes = (size_t)(p - (char*)d_ws);

    // pick the largest T-chunk whose xg2 buffer fits the remaining workspace
    int CHUNK = 8;
    {
        size_t avail = (ws_size > fixedBytes) ? ws_size - fixedBytes : 0;
        const int cands[6] = {512, 256, 128, 64, 32, 16};
        for (int i = 0; i < 6; i++) {
            size_t need = (size_t)cands[i] * BATCH * NR2 * 2;
            if (need <= avail) { CHUNK = cands[i]; break; }
        }
    }
    _Float16* xg2c = (_Float16*)p;

    int prep_n = W1_DW * NR1 + W2_DW * NR2;
    hipLaunchKernelGGL(prep_kernel, dim3((prep_n + 255) / 256), dim3(256), 0, stream,
                       W_hh1, W_ih2, W_hh2, w1t, w2t);
    hipLaunchKernelGGL(lstm1_kernel, dim3(BATCH), dim3(NR1), 0, stream,
                       x, W_ih1, w1t, b_ih1, b_hh1, h1relu);

    const unsigned int* h1dw = (const unsigned int*)h1relu;
    int nch = T_STEPS / CHUNK;
    for (int c2 = 0; c2 < nch; c2++) {
        hipLaunchKernelGGL(xg2_kernel, dim3(1024), dim3(512), 0, stream,
                           h1dw, w2t, b_ih2, b_hh2, xg2c,
                           c2 * CHUNK, CHUNK / 2);
        hipLaunchKernelGGL(lstm2_kernel, dim3(512), dim3(448), 0, stream,
                           xg2c, w2t, cstate, hstate, h2last,
                           CHUNK, (c2 == 0) ? 1 : 0, (c2 == nch - 1) ? 1 : 0);
    }
    hipLaunchKernelGGL(head_kernel, dim3(BATCH / 64), dim3(64), 0, stream,
                       h2last, W_l1, b_l1, W_l2, b_l2, out);
}